// Round 15
// baseline (407.691 us; speedup 1.0000x reference)
//
#include <hip/hip_runtime.h>

#define DIM   2048
#define LSEQ  4096
#define BATCH 4
#define NTOK  (BATCH*LSEQ)        // 16384
#define NCH   16
#define CHL   (LSEQ/NCH)          // 256
#define PI_F  3.14159265358979f
#define NT    (DIM/64)            // 32 K-tiles of 64

typedef __bf16 bf16x8 __attribute__((ext_vector_type(8)));
typedef float  f32x2  __attribute__((ext_vector_type(2)));
typedef float  f32x4  __attribute__((ext_vector_type(4)));
typedef float  f32x8  __attribute__((ext_vector_type(8)));
typedef unsigned short ushort2_t __attribute__((ext_vector_type(2)));
typedef unsigned short ushort8 __attribute__((ext_vector_type(8)));

__device__ __forceinline__ unsigned short f2bf(float f) {
    unsigned int u = __float_as_uint(f);
    u += 0x7fffu + ((u >> 16) & 1u);       // round-to-nearest-even
    return (unsigned short)(u >> 16);
}
__device__ __forceinline__ float bf2f(unsigned short u) {
    return __uint_as_float((unsigned int)u << 16);
}

__device__ __forceinline__ void gload_lds16(const void* g, void* l) {
    __builtin_amdgcn_global_load_lds(
        (const __attribute__((address_space(1))) void*)g,
        (__attribute__((address_space(3))) void*)l, 16, 0, 0);
}

// ---------------- W [K][N] fp32 -> W^T [N][K] bf16 (both weights, grid.z selects) ----------------
__global__ __launch_bounds__(256) void k_transpose2(const float* __restrict__ srcV,
                                                    unsigned short* __restrict__ dstV,
                                                    const float* __restrict__ srcO,
                                                    unsigned short* __restrict__ dstO) {
    __shared__ float tile[32][33];
    const float* src = blockIdx.z ? srcO : srcV;
    unsigned short* dst = blockIdx.z ? dstO : dstV;
    int tx = threadIdx.x, ty = threadIdx.y;
    int k0 = blockIdx.y * 32, n0 = blockIdx.x * 32;
#pragma unroll
    for (int r = 0; r < 4; r++)
        tile[ty + r * 8][tx] = src[(size_t)(k0 + ty + r * 8) * DIM + n0 + tx];
    __syncthreads();
#pragma unroll
    for (int r = 0; r < 4; r++)
        dst[(size_t)(n0 + ty + r * 8) * DIM + k0 + tx] = f2bf(tile[tx][ty + r * 8]);
}

// ---------------- W_paT[16][2048] bf16 ----------------
__global__ __launch_bounds__(256) void k_prep_wpa(const float* __restrict__ Wp,
                                                  const float* __restrict__ Wa,
                                                  unsigned short* __restrict__ WpaT) {
    int idx = blockIdx.x * 256 + threadIdx.x;
    int p = idx >> 11, k = idx & (DIM - 1);
    float v = (p < 8) ? Wp[(size_t)k * 8 + p] : Wa[(size_t)k * 8 + (p - 8)];
    WpaT[idx] = f2bf(v);
}

// ---- sproj via MFMA: Z = x @ [Wp|Wa] (16-wide), fused x->bf16 emit ----
__global__ __launch_bounds__(256) void k_sproj_mfma(const float* __restrict__ x,
                                                    const unsigned short* __restrict__ WpaT,
                                                    const float* __restrict__ bp,
                                                    const float* __restrict__ ba,
                                                    float* __restrict__ s,
                                                    unsigned short* __restrict__ xbf) {
    const int t = threadIdx.x;
    const int w = t >> 6, l = t & 63;
    const int r16 = l & 15, q = l >> 4;
    const int rowbase = blockIdx.x * 64 + w * 16;
    const float* xr = x + (size_t)(rowbase + r16) * DIM + q * 8;
    unsigned short* xw = xbf + (size_t)(rowbase + r16) * DIM + q * 8;
    const unsigned short* wrow = WpaT + r16 * DIM + q * 8;

    f32x4 acc = {};
#pragma unroll 8
    for (int ks = 0; ks < 64; ks++) {
        f32x8 xv = *(const f32x8*)(xr + ks * 32);
        ushort8 xo;
#pragma unroll
        for (int j = 0; j < 8; j++) xo[j] = f2bf(xv[j]);
        *(ushort8*)(xw + ks * 32) = xo;
        bf16x8 av = *(const bf16x8*)&xo;
        bf16x8 bv = *(const bf16x8*)(wrow + ks * 32);
        acc = __builtin_amdgcn_mfma_f32_16x16x32_bf16(av, bv, acc, 0, 0, 0);
    }
    const float bpv = bp[r16 & 7], bav = ba[r16 & 7];
#pragma unroll
    for (int j = 0; j < 4; j++) {
        float z = acc[j];
        float zo = __shfl_xor(z, 8);
        float zp = z + bpv, za = zo + bav;
        float ph = tanhf(zp) * PI_F;
        float amp = (za > 20.f ? za : log1pf(expf(za))) + 0.1f;
        float term = (r16 < 8) ? (cosf(ph) + sinf(ph)) * amp : 0.f;
        term += __shfl_xor(term, 1);
        term += __shfl_xor(term, 2);
        term += __shfl_xor(term, 4);
        if (r16 == 0) s[rowbase + q * 4 + j] = term;
    }
}

// ---------------- 256x256 bf16 MFMA GEMM: measured-best config (163us), frozen ----------------
// 4 phases/K-tile, reg-pipelined fragments (aA/aB,bA/bB), 1 barrier/phase, vmcnt(4)/phase.
// Row-band XCD swizzle (FETCH 136MB ~= 134MB ideal). LDS [slot][kh][256][32],
// XOR swizzle phys_q = q ^ ((row>>1)&3) (bank conflicts = 0).
__device__ __forceinline__ void stage_unit(const unsigned short* __restrict__ src,
                                           unsigned short* dst, int tid) {
    gload_lds16(src,                     dst + tid * 8);
    gload_lds16(src + (size_t)128 * DIM, dst + (tid + 512) * 8);
}

template <int EPI>
__global__ __launch_bounds__(512, 2) void k_gemm256(const unsigned short* __restrict__ A,
                                                    const unsigned short* __restrict__ Bt,
                                                    const float* __restrict__ bias,
                                                    const float* __restrict__ sc,
                                                    const unsigned short* __restrict__ residbf,
                                                    float* __restrict__ C,
                                                    unsigned short* __restrict__ Cbf,
                                                    float* __restrict__ part) {
    __shared__ __align__(16) unsigned short As[2][2][256 * 32];
    __shared__ __align__(16) unsigned short Bs[2][2][256 * 32];
    __shared__ float colsum[2][256];
    const int tid = threadIdx.x;
    const int w = tid >> 6, lane = tid & 63;
    const int wm = w >> 2, wn = w & 3;
    const int r16 = lane & 15, q = lane >> 4;

    int bid = blockIdx.x;
    int wgs = (bid & 7) * 64 + (bid >> 3);        // bijective XCD swizzle (512 % 8 == 0)
    int tm = wgs >> 3, tn = wgs & 7;
    int brow = tm * 256, bcol = tn * 256;

    const int kq = ((tid & 3) ^ ((tid >> 3) & 3)) * 8;
    const unsigned short* pA = A  + (size_t)(brow + (tid >> 2)) * DIM + kq;
    const unsigned short* pB = Bt + (size_t)(bcol + (tid >> 2)) * DIM + kq;

    const int qs8 = (q ^ ((r16 >> 1) & 3)) * 8;
    const int offA = (wm * 128 + r16) * 32 + qs8;
    const int offB = (wn * 64  + r16) * 32 + qs8;

    f32x4 acc[8][4] = {};
    bf16x8 aA[4], aB[4], bA[4], bB[4];

    // prologue: A-K0(0), B-K0(0), A-K1(0), B-K1(0), A-K0(1) = 10 loads in flight
    stage_unit(pA,      &As[0][0][0], tid);
    stage_unit(pB,      &Bs[0][0][0], tid);
    stage_unit(pA + 32, &As[0][1][0], tid);
    stage_unit(pB + 32, &Bs[0][1][0], tid);
    stage_unit(pA + 64, &As[1][0][0], tid);
    asm volatile("s_waitcnt vmcnt(6)" ::: "memory");    // K0(0) pair landed
    __builtin_amdgcn_s_barrier();
    // preload tile-0 (C0,k0) + k0 B fragments
#pragma unroll
    for (int i = 0; i < 4; i++) aA[i] = *(const bf16x8*)(&As[0][0][0] + offA + i * 512);
#pragma unroll
    for (int n = 0; n < 4; n++) bA[n] = *(const bf16x8*)(&Bs[0][0][0] + offB + n * 512);

#pragma unroll 2
    for (int t = 0; t < NT; ++t) {
        const int s = t & 1;
        unsigned short* A0 = &As[s][0][0];
        unsigned short* A1 = &As[s][1][0];
        unsigned short* B1 = &Bs[s][1][0];
        unsigned short* nA0 = &As[s ^ 1][0][0];
        unsigned short* nB0 = &Bs[s ^ 1][0][0];

        // ---- phase 0: MFMA (C0,k0) = aA x bA ; read-ahead aB <- (C1,k0) ----
        stage_unit(pB + (t + 1) * 64, nB0, tid);                       // B-K0(t+1)
#pragma unroll
        for (int i = 0; i < 4; i++) aB[i] = *(const bf16x8*)(A0 + offA + 2048 + i * 512);
        __builtin_amdgcn_s_setprio(1);
#pragma unroll
        for (int i = 0; i < 4; i++)
#pragma unroll
            for (int n = 0; n < 4; n++)
                acc[i][n] = __builtin_amdgcn_mfma_f32_16x16x32_bf16(aA[i], bA[n], acc[i][n], 0, 0, 0);
        __builtin_amdgcn_s_setprio(0);
        asm volatile("s_waitcnt vmcnt(4)" ::: "memory");
        __builtin_amdgcn_s_barrier();

        // ---- phase 1: MFMA (C1,k0) = aB x bA ; read-ahead aA <- (C0,k1), bB <- k1 ----
        stage_unit(pA + (t + 1) * 64 + 32, &As[s ^ 1][1][0], tid);     // A-K1(t+1)
#pragma unroll
        for (int i = 0; i < 4; i++) aA[i] = *(const bf16x8*)(A1 + offA + i * 512);
#pragma unroll
        for (int n = 0; n < 4; n++) bB[n] = *(const bf16x8*)(B1 + offB + n * 512);
        __builtin_amdgcn_s_setprio(1);
#pragma unroll
        for (int i = 0; i < 4; i++)
#pragma unroll
            for (int n = 0; n < 4; n++)
                acc[4 + i][n] = __builtin_amdgcn_mfma_f32_16x16x32_bf16(aB[i], bA[n], acc[4 + i][n], 0, 0, 0);
        __builtin_amdgcn_s_setprio(0);
        asm volatile("s_waitcnt vmcnt(4)" ::: "memory");
        __builtin_amdgcn_s_barrier();

        // ---- phase 2: MFMA (C0,k1) = aA x bB ; read-ahead aB <- (C1,k1) ----
        stage_unit(pB + (t + 1) * 64 + 32, &Bs[s ^ 1][1][0], tid);     // B-K1(t+1)
#pragma unroll
        for (int i = 0; i < 4; i++) aB[i] = *(const bf16x8*)(A1 + offA + 2048 + i * 512);
        __builtin_amdgcn_s_setprio(1);
#pragma unroll
        for (int i = 0; i < 4; i++)
#pragma unroll
            for (int n = 0; n < 4; n++)
                acc[i][n] = __builtin_amdgcn_mfma_f32_16x16x32_bf16(aA[i], bB[n], acc[i][n], 0, 0, 0);
        __builtin_amdgcn_s_setprio(0);
        asm volatile("s_waitcnt vmcnt(4)" ::: "memory");
        __builtin_amdgcn_s_barrier();

        // ---- phase 3: MFMA (C1,k1) = aB x bB ; read-ahead aA,bA <- next tile (C0,k0),k0 ----
        stage_unit(pA + (t + 2) * 64, A0, tid);                        // A-K0(t+2), own slot kh0
#pragma unroll
        for (int i = 0; i < 4; i++) aA[i] = *(const bf16x8*)(nA0 + offA + i * 512);
#pragma unroll
        for (int n = 0; n < 4; n++) bA[n] = *(const bf16x8*)(nB0 + offB + n * 512);
        __builtin_amdgcn_s_setprio(1);
#pragma unroll
        for (int i = 0; i < 4; i++)
#pragma unroll
            for (int n = 0; n < 4; n++)
                acc[4 + i][n] = __builtin_amdgcn_mfma_f32_16x16x32_bf16(aB[i], bB[n], acc[4 + i][n], 0, 0, 0);
        __builtin_amdgcn_s_setprio(0);
        asm volatile("s_waitcnt vmcnt(4)" ::: "memory");
        __builtin_amdgcn_s_barrier();
    }
    asm volatile("s_waitcnt vmcnt(0) lgkmcnt(0)" ::: "memory");  // retire phantom tail ops

    // epilogue: frag row = q*4+j, col = r16 (verified convention)
    float cs[4] = {0.f, 0.f, 0.f, 0.f};
#pragma unroll
    for (int mf = 0; mf < 8; mf++) {
        int r0 = brow + wm * 128 + mf * 16 + q * 4;
#pragma unroll
        for (int nf = 0; nf < 4; nf++) {
            int c = bcol + wn * 64 + nf * 16 + r16;
            float bc = bias[c];
#pragma unroll
            for (int j = 0; j < 4; j++) {
                int r = r0 + j;
                float v = acc[mf][nf][j] + bc;
                if (EPI == 0) {
                    v *= sc[r];
                    cs[nf] += v;
                    Cbf[(size_t)r * DIM + c] = f2bf(v);
                } else {
                    v += bf2f(residbf[(size_t)r * DIM + c]);
                    C[(size_t)r * DIM + c] = v;
                }
            }
        }
    }
    if (EPI == 0) {   // fused scan_partial: column sums of this 256x256 tile
#pragma unroll
        for (int nf = 0; nf < 4; nf++) {
            float v = cs[nf];
            v += __shfl_xor(v, 16);           // reduce over q
            v += __shfl_xor(v, 32);
            if (q == 0) colsum[wm][wn * 64 + nf * 16 + r16] = v;
        }
        __syncthreads();
        if (tid < 256)
            part[(size_t)(brow >> 8) * DIM + bcol + tid] = colsum[0][tid] + colsum[1][tid];
    }
}

// ---------------- cumsum over L: chunk-offset scan + in-place apply (bf16, x2-vectorized) ----------------
__global__ __launch_bounds__(256) void k_scan_offsets(float* __restrict__ part) {
    int tid = blockIdx.x * 256 + threadIdx.x;  // BATCH*DIM/2 threads
    int d = (tid & (DIM / 2 - 1)) * 2;
    int b = tid >> 10;
    float r0 = 0.f, r1 = 0.f;
    for (int ch = 0; ch < NCH; ch++) {
        size_t idx = ((size_t)b * NCH + ch) * DIM + d;
        f32x2 v = *(const f32x2*)(part + idx);
        f32x2 o; o[0] = r0; o[1] = r1;
        *(f32x2*)(part + idx) = o;
        r0 += v[0]; r1 += v[1];
    }
}

__global__ __launch_bounds__(256) void k_scan_apply(unsigned short* __restrict__ boundbf,
                                                    const float* __restrict__ part) {
    int tid = blockIdx.x * 256 + threadIdx.x;  // BATCH*NCH*DIM/2 threads
    int d = (tid & (DIM / 2 - 1)) * 2;
    int ch = (tid >> 10) & (NCH - 1);
    int b = tid >> 14;
    size_t pidx = ((size_t)b * NCH + ch) * DIM + d;
    float r0 = part[pidx], r1 = part[pidx + 1];
    unsigned short* p = boundbf + ((size_t)b * LSEQ + (size_t)ch * CHL) * DIM + d;
    for (int i = 0; i < CHL; i++) {             // in-place: thread owns these 2 column slices
        ushort2_t v = *(ushort2_t*)(p + (size_t)i * DIM);
        r0 += bf2f(v[0]); r1 += bf2f(v[1]);
        ushort2_t o; o[0] = f2bf(r0); o[1] = f2bf(r1);
        *(ushort2_t*)(p + (size_t)i * DIM) = o;
    }
}

// ---------------- LayerNorm(retrieved_bf/64) -> h bf16 : one WAVE per row, no LDS ----------------
__global__ __launch_bounds__(256) void k_lnorm(const unsigned short* __restrict__ retbf,
                                               const float* __restrict__ g,
                                               const float* __restrict__ bta,
                                               unsigned short* __restrict__ h) {
    const int t = threadIdx.x;
    const int w = t >> 6, l = t & 63;
    const int row = blockIdx.x * 4 + w;
    const unsigned short* pr = retbf + (size_t)row * DIM + l * 8;   // lane: 4 chunks of 512
    const float scl = 1.0f / 64.0f;   // 1/sqrt(L)
    float vv[32];
    float sum = 0.f, ss = 0.f;
#pragma unroll
    for (int c = 0; c < 4; c++) {
        ushort8 rv = *(const ushort8*)(pr + c * 512);
#pragma unroll
        for (int j = 0; j < 8; j++) {
            float v = bf2f(rv[j]) * scl;
            vv[c * 8 + j] = v;
            sum += v; ss += v * v;
        }
    }
#pragma unroll
    for (int off = 32; off; off >>= 1) { sum += __shfl_xor(sum, off); ss += __shfl_xor(ss, off); }
    float mu = sum / DIM;
    float rstd = rsqrtf(ss / DIM - mu * mu + 1e-5f);
    unsigned short* ph = h + (size_t)row * DIM + l * 8;
#pragma unroll
    for (int c = 0; c < 4; c++) {
        f32x8 gv = *(const f32x8*)(g + l * 8 + c * 512);
        f32x8 bv = *(const f32x8*)(bta + l * 8 + c * 512);
        ushort8 o;
#pragma unroll
        for (int j = 0; j < 8; j++) o[j] = f2bf((vv[c * 8 + j] - mu) * rstd * gv[j] + bv[j]);
        *(ushort8*)(ph + c * 512) = o;
    }
}

extern "C" void kernel_launch(void* const* d_in, const int* in_sizes, int n_in,
                              void* d_out, int out_size, void* d_ws, size_t ws_size,
                              hipStream_t stream) {
    const float* x   = (const float*)d_in[0];
    const float* Wp  = (const float*)d_in[1];
    const float* bp  = (const float*)d_in[2];
    const float* Wa  = (const float*)d_in[3];
    const float* ba  = (const float*)d_in[4];
    const float* Wv  = (const float*)d_in[5];
    const float* bv  = (const float*)d_in[6];
    const float* lng = (const float*)d_in[7];
    const float* lnb = (const float*)d_in[8];
    const float* Wo  = (const float*)d_in[9];
    const float* bo  = (const float*)d_in[10];
    float* out = (float*)d_out;

    char* ws = (char*)d_ws;
    unsigned short* x_bf  = (unsigned short*)ws; ws += (size_t)NTOK * DIM * 2;   // bf16 x (A0, resid1)
    unsigned short* h_bf  = (unsigned short*)ws; ws += (size_t)NTOK * DIM * 2;   // lnorm out (A1)
    unsigned short* WvT   = (unsigned short*)ws; ws += (size_t)DIM * DIM * 2;
    unsigned short* WoT   = (unsigned short*)ws; ws += (size_t)DIM * DIM * 2;
    unsigned short* WpaT  = (unsigned short*)ws; ws += (size_t)16 * DIM * 2;
    float* svec           = (float*)ws;          ws += (size_t)NTOK * 4;
    unsigned short* bound = (unsigned short*)ws; ws += (size_t)NTOK * DIM * 2;   // bf16 bound -> retrieved (in-place)
    float* part           = (float*)ws;          ws += (size_t)BATCH * NCH * DIM * 4;

    dim3 tb(32, 8);
    k_transpose2<<<dim3(64, 64, 2), tb, 0, stream>>>(Wv, WvT, Wo, WoT);
    k_prep_wpa<<<128, 256, 0, stream>>>(Wp, Wa, WpaT);
    k_sproj_mfma<<<NTOK / 64, 256, 0, stream>>>(x, WpaT, bp, ba, svec, x_bf);

    k_gemm256<0><<<512, 512, 0, stream>>>(x_bf, WvT, bv, svec, nullptr, nullptr, bound, part);

    k_scan_offsets<<<BATCH * DIM / 512, 256, 0, stream>>>(part);
    k_scan_apply<<<BATCH * NCH * DIM / 512, 256, 0, stream>>>(bound, part);

    k_lnorm<<<NTOK / 4, 256, 0, stream>>>(bound, lng, lnb, h_bf);

    k_gemm256<1><<<512, 512, 0, stream>>>(h_bf, WoT, bo, nullptr, x_bf, out, nullptr, nullptr);
}

// Round 16
// 399.103 us; speedup vs baseline: 1.0215x; 1.0215x over previous
//
#include <hip/hip_runtime.h>

#define DIM   2048
#define LSEQ  4096
#define BATCH 4
#define NTOK  (BATCH*LSEQ)        // 16384
#define NCH   16
#define CHL   (LSEQ/NCH)          // 256
#define PI_F  3.14159265358979f
#define NT    (DIM/64)            // 32 K-tiles of 64

typedef __bf16 bf16x8 __attribute__((ext_vector_type(8)));
typedef float  f32x4  __attribute__((ext_vector_type(4)));
typedef float  f32x8  __attribute__((ext_vector_type(8)));
typedef unsigned short ushort8 __attribute__((ext_vector_type(8)));

__device__ __forceinline__ unsigned short f2bf(float f) {
    unsigned int u = __float_as_uint(f);
    u += 0x7fffu + ((u >> 16) & 1u);       // round-to-nearest-even
    return (unsigned short)(u >> 16);
}
__device__ __forceinline__ float bf2f(unsigned short u) {
    return __uint_as_float((unsigned int)u << 16);
}

__device__ __forceinline__ void gload_lds16(const void* g, void* l) {
    __builtin_amdgcn_global_load_lds(
        (const __attribute__((address_space(1))) void*)g,
        (__attribute__((address_space(3))) void*)l, 16, 0, 0);
}

// ---------------- W [K][N] fp32 -> W^T [N][K] bf16 (both weights, grid.z selects) ----------------
__global__ __launch_bounds__(256) void k_transpose2(const float* __restrict__ srcV,
                                                    unsigned short* __restrict__ dstV,
                                                    const float* __restrict__ srcO,
                                                    unsigned short* __restrict__ dstO) {
    __shared__ float tile[32][33];
    const float* src = blockIdx.z ? srcO : srcV;
    unsigned short* dst = blockIdx.z ? dstO : dstV;
    int tx = threadIdx.x, ty = threadIdx.y;
    int k0 = blockIdx.y * 32, n0 = blockIdx.x * 32;
#pragma unroll
    for (int r = 0; r < 4; r++)
        tile[ty + r * 8][tx] = src[(size_t)(k0 + ty + r * 8) * DIM + n0 + tx];
    __syncthreads();
#pragma unroll
    for (int r = 0; r < 4; r++)
        dst[(size_t)(n0 + ty + r * 8) * DIM + k0 + tx] = f2bf(tile[tx][ty + r * 8]);
}

// ---------------- W_paT[16][2048] bf16 ----------------
__global__ __launch_bounds__(256) void k_prep_wpa(const float* __restrict__ Wp,
                                                  const float* __restrict__ Wa,
                                                  unsigned short* __restrict__ WpaT) {
    int idx = blockIdx.x * 256 + threadIdx.x;
    int p = idx >> 11, k = idx & (DIM - 1);
    float v = (p < 8) ? Wp[(size_t)k * 8 + p] : Wa[(size_t)k * 8 + (p - 8)];
    WpaT[idx] = f2bf(v);
}

// ---- sproj via MFMA: Z = x @ [Wp|Wa] (16-wide), fused x->bf16 emit ----
__global__ __launch_bounds__(256) void k_sproj_mfma(const float* __restrict__ x,
                                                    const unsigned short* __restrict__ WpaT,
                                                    const float* __restrict__ bp,
                                                    const float* __restrict__ ba,
                                                    float* __restrict__ s,
                                                    unsigned short* __restrict__ xbf) {
    const int t = threadIdx.x;
    const int w = t >> 6, l = t & 63;
    const int r16 = l & 15, q = l >> 4;
    const int rowbase = blockIdx.x * 64 + w * 16;
    const float* xr = x + (size_t)(rowbase + r16) * DIM + q * 8;
    unsigned short* xw = xbf + (size_t)(rowbase + r16) * DIM + q * 8;
    const unsigned short* wrow = WpaT + r16 * DIM + q * 8;

    f32x4 acc = {};
#pragma unroll 8
    for (int ks = 0; ks < 64; ks++) {
        f32x8 xv = *(const f32x8*)(xr + ks * 32);
        ushort8 xo;
#pragma unroll
        for (int j = 0; j < 8; j++) xo[j] = f2bf(xv[j]);
        *(ushort8*)(xw + ks * 32) = xo;
        bf16x8 av = *(const bf16x8*)&xo;
        bf16x8 bv = *(const bf16x8*)(wrow + ks * 32);
        acc = __builtin_amdgcn_mfma_f32_16x16x32_bf16(av, bv, acc, 0, 0, 0);
    }
    const float bpv = bp[r16 & 7], bav = ba[r16 & 7];
#pragma unroll
    for (int j = 0; j < 4; j++) {
        float z = acc[j];
        float zo = __shfl_xor(z, 8);
        float zp = z + bpv, za = zo + bav;
        float ph = tanhf(zp) * PI_F;
        float amp = (za > 20.f ? za : log1pf(expf(za))) + 0.1f;
        float term = (r16 < 8) ? (cosf(ph) + sinf(ph)) * amp : 0.f;
        term += __shfl_xor(term, 1);
        term += __shfl_xor(term, 2);
        term += __shfl_xor(term, 4);
        if (r16 == 0) s[rowbase + q * 4 + j] = term;
    }
}

// ---------------- 256x256 bf16 MFMA GEMM: measured-best config (163us), frozen ----------------
// 4 phases/K-tile, reg-pipelined fragments (aA/aB,bA/bB), 1 barrier/phase, vmcnt(4)/phase.
// Row-band XCD swizzle (FETCH 136MB ~= 134MB ideal). LDS [slot][kh][256][32],
// XOR swizzle phys_q = q ^ ((row>>1)&3) (bank conflicts = 0).
__device__ __forceinline__ void stage_unit(const unsigned short* __restrict__ src,
                                           unsigned short* dst, int tid) {
    gload_lds16(src,                     dst + tid * 8);
    gload_lds16(src + (size_t)128 * DIM, dst + (tid + 512) * 8);
}

template <int EPI>
__global__ __launch_bounds__(512, 2) void k_gemm256(const unsigned short* __restrict__ A,
                                                    const unsigned short* __restrict__ Bt,
                                                    const float* __restrict__ bias,
                                                    const float* __restrict__ sc,
                                                    const unsigned short* __restrict__ residbf,
                                                    float* __restrict__ C,
                                                    unsigned short* __restrict__ Cbf,
                                                    float* __restrict__ part) {
    __shared__ __align__(16) unsigned short As[2][2][256 * 32];
    __shared__ __align__(16) unsigned short Bs[2][2][256 * 32];
    __shared__ float colsum[2][256];
    const int tid = threadIdx.x;
    const int w = tid >> 6, lane = tid & 63;
    const int wm = w >> 2, wn = w & 3;
    const int r16 = lane & 15, q = lane >> 4;

    int bid = blockIdx.x;
    int wgs = (bid & 7) * 64 + (bid >> 3);        // bijective XCD swizzle (512 % 8 == 0)
    int tm = wgs >> 3, tn = wgs & 7;
    int brow = tm * 256, bcol = tn * 256;

    const int kq = ((tid & 3) ^ ((tid >> 3) & 3)) * 8;
    const unsigned short* pA = A  + (size_t)(brow + (tid >> 2)) * DIM + kq;
    const unsigned short* pB = Bt + (size_t)(bcol + (tid >> 2)) * DIM + kq;

    const int qs8 = (q ^ ((r16 >> 1) & 3)) * 8;
    const int offA = (wm * 128 + r16) * 32 + qs8;
    const int offB = (wn * 64  + r16) * 32 + qs8;

    f32x4 acc[8][4] = {};
    bf16x8 aA[4], aB[4], bA[4], bB[4];

    // prologue: A-K0(0), B-K0(0), A-K1(0), B-K1(0), A-K0(1) = 10 loads in flight
    stage_unit(pA,      &As[0][0][0], tid);
    stage_unit(pB,      &Bs[0][0][0], tid);
    stage_unit(pA + 32, &As[0][1][0], tid);
    stage_unit(pB + 32, &Bs[0][1][0], tid);
    stage_unit(pA + 64, &As[1][0][0], tid);
    asm volatile("s_waitcnt vmcnt(6)" ::: "memory");    // K0(0) pair landed
    __builtin_amdgcn_s_barrier();
    // preload tile-0 (C0,k0) + k0 B fragments
#pragma unroll
    for (int i = 0; i < 4; i++) aA[i] = *(const bf16x8*)(&As[0][0][0] + offA + i * 512);
#pragma unroll
    for (int n = 0; n < 4; n++) bA[n] = *(const bf16x8*)(&Bs[0][0][0] + offB + n * 512);

#pragma unroll 2
    for (int t = 0; t < NT; ++t) {
        const int s = t & 1;
        unsigned short* A0 = &As[s][0][0];
        unsigned short* A1 = &As[s][1][0];
        unsigned short* B1 = &Bs[s][1][0];
        unsigned short* nA0 = &As[s ^ 1][0][0];
        unsigned short* nB0 = &Bs[s ^ 1][0][0];

        // ---- phase 0: MFMA (C0,k0) = aA x bA ; read-ahead aB <- (C1,k0) ----
        stage_unit(pB + (t + 1) * 64, nB0, tid);                       // B-K0(t+1)
#pragma unroll
        for (int i = 0; i < 4; i++) aB[i] = *(const bf16x8*)(A0 + offA + 2048 + i * 512);
        __builtin_amdgcn_s_setprio(1);
#pragma unroll
        for (int i = 0; i < 4; i++)
#pragma unroll
            for (int n = 0; n < 4; n++)
                acc[i][n] = __builtin_amdgcn_mfma_f32_16x16x32_bf16(aA[i], bA[n], acc[i][n], 0, 0, 0);
        __builtin_amdgcn_s_setprio(0);
        asm volatile("s_waitcnt vmcnt(4)" ::: "memory");
        __builtin_amdgcn_s_barrier();

        // ---- phase 1: MFMA (C1,k0) = aB x bA ; read-ahead aA <- (C0,k1), bB <- k1 ----
        stage_unit(pA + (t + 1) * 64 + 32, &As[s ^ 1][1][0], tid);     // A-K1(t+1)
#pragma unroll
        for (int i = 0; i < 4; i++) aA[i] = *(const bf16x8*)(A1 + offA + i * 512);
#pragma unroll
        for (int n = 0; n < 4; n++) bB[n] = *(const bf16x8*)(B1 + offB + n * 512);
        __builtin_amdgcn_s_setprio(1);
#pragma unroll
        for (int i = 0; i < 4; i++)
#pragma unroll
            for (int n = 0; n < 4; n++)
                acc[4 + i][n] = __builtin_amdgcn_mfma_f32_16x16x32_bf16(aB[i], bA[n], acc[4 + i][n], 0, 0, 0);
        __builtin_amdgcn_s_setprio(0);
        asm volatile("s_waitcnt vmcnt(4)" ::: "memory");
        __builtin_amdgcn_s_barrier();

        // ---- phase 2: MFMA (C0,k1) = aA x bB ; read-ahead aB <- (C1,k1) ----
        stage_unit(pB + (t + 1) * 64 + 32, &Bs[s ^ 1][1][0], tid);     // B-K1(t+1)
#pragma unroll
        for (int i = 0; i < 4; i++) aB[i] = *(const bf16x8*)(A1 + offA + 2048 + i * 512);
        __builtin_amdgcn_s_setprio(1);
#pragma unroll
        for (int i = 0; i < 4; i++)
#pragma unroll
            for (int n = 0; n < 4; n++)
                acc[i][n] = __builtin_amdgcn_mfma_f32_16x16x32_bf16(aA[i], bB[n], acc[i][n], 0, 0, 0);
        __builtin_amdgcn_s_setprio(0);
        asm volatile("s_waitcnt vmcnt(4)" ::: "memory");
        __builtin_amdgcn_s_barrier();

        // ---- phase 3: MFMA (C1,k1) = aB x bB ; read-ahead aA,bA <- next tile (C0,k0),k0 ----
        stage_unit(pA + (t + 2) * 64, A0, tid);                        // A-K0(t+2), own slot kh0
#pragma unroll
        for (int i = 0; i < 4; i++) aA[i] = *(const bf16x8*)(nA0 + offA + i * 512);
#pragma unroll
        for (int n = 0; n < 4; n++) bA[n] = *(const bf16x8*)(nB0 + offB + n * 512);
        __builtin_amdgcn_s_setprio(1);
#pragma unroll
        for (int i = 0; i < 4; i++)
#pragma unroll
            for (int n = 0; n < 4; n++)
                acc[4 + i][n] = __builtin_amdgcn_mfma_f32_16x16x32_bf16(aB[i], bB[n], acc[4 + i][n], 0, 0, 0);
        __builtin_amdgcn_s_setprio(0);
        asm volatile("s_waitcnt vmcnt(4)" ::: "memory");
        __builtin_amdgcn_s_barrier();
    }
    asm volatile("s_waitcnt vmcnt(0) lgkmcnt(0)" ::: "memory");  // retire phantom tail ops

    // epilogue: frag row = q*4+j, col = r16 (verified convention)
    float cs[4] = {0.f, 0.f, 0.f, 0.f};
#pragma unroll
    for (int mf = 0; mf < 8; mf++) {
        int r0 = brow + wm * 128 + mf * 16 + q * 4;
#pragma unroll
        for (int nf = 0; nf < 4; nf++) {
            int c = bcol + wn * 64 + nf * 16 + r16;
            float bc = bias[c];
#pragma unroll
            for (int j = 0; j < 4; j++) {
                int r = r0 + j;
                float v = acc[mf][nf][j] + bc;
                if (EPI == 0) {
                    v *= sc[r];
                    cs[nf] += v;
                    Cbf[(size_t)r * DIM + c] = f2bf(v);
                } else {
                    v += bf2f(residbf[(size_t)r * DIM + c]);
                    C[(size_t)r * DIM + c] = v;
                }
            }
        }
    }
    if (EPI == 0) {   // fused scan_partial: column sums of this 256x256 tile
#pragma unroll
        for (int nf = 0; nf < 4; nf++) {
            float v = cs[nf];
            v += __shfl_xor(v, 16);           // reduce over q
            v += __shfl_xor(v, 32);
            if (q == 0) colsum[wm][wn * 64 + nf * 16 + r16] = v;
        }
        __syncthreads();
        if (tid < 256)
            part[(size_t)(brow >> 8) * DIM + bcol + tid] = colsum[0][tid] + colsum[1][tid];
    }
}

// ---------------- cumsum over L: chunk-offset scan + in-place apply (bf16) ----------------
__global__ __launch_bounds__(256) void k_scan_offsets(float* __restrict__ part) {
    int tid = blockIdx.x * 256 + threadIdx.x;  // (b, d)
    int d = tid & (DIM - 1);
    int b = tid >> 11;
    float run = 0.f;
    for (int ch = 0; ch < NCH; ch++) {
        size_t idx = ((size_t)b * NCH + ch) * DIM + d;
        float v = part[idx];
        part[idx] = run;
        run += v;
    }
}

__global__ __launch_bounds__(256) void k_scan_apply(unsigned short* __restrict__ boundbf,
                                                    const float* __restrict__ part) {
    int tid = blockIdx.x * 256 + threadIdx.x;
    int d = tid & (DIM - 1);
    int ch = (tid >> 11) & (NCH - 1);
    int b = tid >> 15;
    float run = part[tid];
    unsigned short* p = boundbf + ((size_t)b * LSEQ + (size_t)ch * CHL) * DIM + d;
    for (int i = 0; i < CHL; i++) {             // in-place: thread owns this column slice
        run += bf2f(p[(size_t)i * DIM]);
        p[(size_t)i * DIM] = f2bf(run);
    }
}

// ---------------- LayerNorm(retrieved_bf/64) -> h bf16 : one WAVE per row, no LDS ----------------
__global__ __launch_bounds__(256) void k_lnorm(const unsigned short* __restrict__ retbf,
                                               const float* __restrict__ g,
                                               const float* __restrict__ bta,
                                               unsigned short* __restrict__ h) {
    const int t = threadIdx.x;
    const int w = t >> 6, l = t & 63;
    const int row = blockIdx.x * 4 + w;
    const unsigned short* pr = retbf + (size_t)row * DIM + l * 8;   // lane: 4 chunks of 512
    const float scl = 1.0f / 64.0f;   // 1/sqrt(L)
    float vv[32];
    float sum = 0.f, ss = 0.f;
#pragma unroll
    for (int c = 0; c < 4; c++) {
        ushort8 rv = *(const ushort8*)(pr + c * 512);
#pragma unroll
        for (int j = 0; j < 8; j++) {
            float v = bf2f(rv[j]) * scl;
            vv[c * 8 + j] = v;
            sum += v; ss += v * v;
        }
    }
#pragma unroll
    for (int off = 32; off; off >>= 1) { sum += __shfl_xor(sum, off); ss += __shfl_xor(ss, off); }
    float mu = sum / DIM;
    float rstd = rsqrtf(ss / DIM - mu * mu + 1e-5f);
    unsigned short* ph = h + (size_t)row * DIM + l * 8;
#pragma unroll
    for (int c = 0; c < 4; c++) {
        f32x8 gv = *(const f32x8*)(g + l * 8 + c * 512);
        f32x8 bv = *(const f32x8*)(bta + l * 8 + c * 512);
        ushort8 o;
#pragma unroll
        for (int j = 0; j < 8; j++) o[j] = f2bf((vv[c * 8 + j] - mu) * rstd * gv[j] + bv[j]);
        *(ushort8*)(ph + c * 512) = o;
    }
}

extern "C" void kernel_launch(void* const* d_in, const int* in_sizes, int n_in,
                              void* d_out, int out_size, void* d_ws, size_t ws_size,
                              hipStream_t stream) {
    const float* x   = (const float*)d_in[0];
    const float* Wp  = (const float*)d_in[1];
    const float* bp  = (const float*)d_in[2];
    const float* Wa  = (const float*)d_in[3];
    const float* ba  = (const float*)d_in[4];
    const float* Wv  = (const float*)d_in[5];
    const float* bv  = (const float*)d_in[6];
    const float* lng = (const float*)d_in[7];
    const float* lnb = (const float*)d_in[8];
    const float* Wo  = (const float*)d_in[9];
    const float* bo  = (const float*)d_in[10];
    float* out = (float*)d_out;

    char* ws = (char*)d_ws;
    unsigned short* x_bf  = (unsigned short*)ws; ws += (size_t)NTOK * DIM * 2;   // bf16 x (A0, resid1)
    unsigned short* h_bf  = (unsigned short*)ws; ws += (size_t)NTOK * DIM * 2;   // lnorm out (A1)
    unsigned short* WvT   = (unsigned short*)ws; ws += (size_t)DIM * DIM * 2;
    unsigned short* WoT   = (unsigned short*)ws; ws += (size_t)DIM * DIM * 2;
    unsigned short* WpaT  = (unsigned short*)ws; ws += (size_t)16 * DIM * 2;
    float* svec           = (float*)ws;          ws += (size_t)NTOK * 4;
    unsigned short* bound = (unsigned short*)ws; ws += (size_t)NTOK * DIM * 2;   // bf16 bound -> retrieved (in-place)
    float* part           = (float*)ws;          ws += (size_t)BATCH * NCH * DIM * 4;

    dim3 tb(32, 8);
    k_transpose2<<<dim3(64, 64, 2), tb, 0, stream>>>(Wv, WvT, Wo, WoT);
    k_prep_wpa<<<128, 256, 0, stream>>>(Wp, Wa, WpaT);
    k_sproj_mfma<<<NTOK / 64, 256, 0, stream>>>(x, WpaT, bp, ba, svec, x_bf);

    k_gemm256<0><<<512, 512, 0, stream>>>(x_bf, WvT, bv, svec, nullptr, nullptr, bound, part);

    k_scan_offsets<<<BATCH * DIM / 256, 256, 0, stream>>>(part);
    k_scan_apply<<<BATCH * NCH * DIM / 256, 256, 0, stream>>>(bound, part);

    k_lnorm<<<NTOK / 4, 256, 0, stream>>>(bound, lng, lnb, h_bf);

    k_gemm256<1><<<512, 512, 0, stream>>>(h_bf, WoT, bo, nullptr, x_bf, out, nullptr, nullptr);
}